// Round 5
// baseline (63.317 us; speedup 1.0000x reference)
//
#include <hip/hip_runtime.h>
#include <math.h>

// NUFFT forward via separable phase + bf16 MFMA. No workspace.
// ksp[c,k] = sum_x Ex[k,x] * ( sum_y img[c,x,y] * Ey[k,y] )
// R5: KB 32->16 (grid 256->512, 2 blocks/CU, 4 waves/SIMD) to attack the
// latency/occupancy bound seen in R4 (MfmaUtil 7%, VALUBusy 17%, Occ 20%).

#define K_TOTAL 8192
#define KB      16          // k's per block (one 16-row M tile)
#define NX      128
#define NY      128
#define EY_LD   136         // bf16 row stride (pad +8)
#define EX_LD   132         // f32 row stride (pad +4)

typedef short  bf16x8 __attribute__((ext_vector_type(8)));
typedef float  f32x4  __attribute__((ext_vector_type(4)));

__device__ inline unsigned short f32_to_bf16_rne(float f) {
    unsigned int u = __float_as_uint(f);
    u += 0x7FFFu + ((u >> 16) & 1u);
    return (unsigned short)(u >> 16);
}

// 8 fp32 -> bf16x8, round-to-nearest-even (proven: absmax 2.0)
__device__ inline bf16x8 cvt8(const float4 a, const float4 b) {
    bf16x8 r;
    r[0] = (short)f32_to_bf16_rne(a.x);
    r[1] = (short)f32_to_bf16_rne(a.y);
    r[2] = (short)f32_to_bf16_rne(a.z);
    r[3] = (short)f32_to_bf16_rne(a.w);
    r[4] = (short)f32_to_bf16_rne(b.x);
    r[5] = (short)f32_to_bf16_rne(b.y);
    r[6] = (short)f32_to_bf16_rne(b.z);
    r[7] = (short)f32_to_bf16_rne(b.w);
    return r;
}

__global__ __launch_bounds__(512, 4) void nufft_mfma_kernel(
    const float* __restrict__ imgR,
    const float* __restrict__ imgI,
    const float* __restrict__ trj,
    float* __restrict__ out)
{
    __shared__ __align__(16) unsigned short eyR[KB][EY_LD];
    __shared__ __align__(16) unsigned short eyI[KB][EY_LD];
    __shared__ __align__(16) float exR[KB][EX_LD];
    __shared__ __align__(16) float exI[KB][EX_LD];

    const int tid = threadIdx.x;
    const int k0  = blockIdx.x * KB;

    // ---- Phase A: exponential tables (Ey bf16, Ex f32) ----
    for (int i = tid; i < KB * 128; i += 512) {
        const int kk = i >> 7;
        const int p  = i & 127;
        const float kx = trj[(k0 + kk) * 2 + 0];
        const float ky = trj[(k0 + kk) * 2 + 1];
        const float r  = (float)(p - 64) * (1.0f / 128.0f);

        float ty = -ky * r; ty -= floorf(ty);
        float sy, cy; __sincosf(6.283185307179586f * ty, &sy, &cy);
        eyR[kk][p] = f32_to_bf16_rne(cy);
        eyI[kk][p] = f32_to_bf16_rne(sy);

        float tx = -kx * r; tx -= floorf(tx);
        float sx, cx; __sincosf(6.283185307179586f * tx, &sx, &cx);
        exR[kk][p] = cx;
        exI[kk][p] = sx;
    }
    __syncthreads();

    const int wave = tid >> 6;      // 0..7  == coil
    const int lane = tid & 63;
    const int l15  = lane & 15;
    const int lg   = lane >> 4;     // 0..3

    // ---- A-fragment preload: Ey into registers (shared across all n-tiles) ----
    // A layout (16x16x32): row = lane&15, k-dim slot = (lane>>4)*8 + idx.
    // A and B use the SAME k slot mapping, so any hw k-permutation cancels.
    bf16x8 aR[4], aI[4];
#pragma unroll
    for (int ys = 0; ys < 4; ++ys) {
        const int y = ys * 32 + lg * 8;
        aR[ys] = *(const bf16x8*)&eyR[l15][y];
        aI[ys] = *(const bf16x8*)&eyI[l15][y];
    }

    const int c = wave;
    f32x4 outRe = {0, 0, 0, 0};
    f32x4 outIm = {0, 0, 0, 0};

    // ---- n-tiles: 8 x-tiles of 16 for this wave's coil ----
    for (int nt = 0; nt < 8; ++nt) {
        const int x = nt * 16 + l15;

        f32x4 P = {0,0,0,0}, Q = {0,0,0,0}, U = {0,0,0,0}, V = {0,0,0,0};

        // B layout: col = lane&15 -> x; k slot y = (lane>>4)*8 + idx, contiguous
        // in img[c][x][y]. Load fp32, convert in registers (RNE).
        const float* baseR = imgR + (c * NX + x) * NY + lg * 8;
        const float* baseI = imgI + (c * NX + x) * NY + lg * 8;

#pragma unroll
        for (int ys = 0; ys < 4; ++ys) {
            const float4 r0 = *(const float4*)(baseR + ys * 32);
            const float4 r1 = *(const float4*)(baseR + ys * 32 + 4);
            const float4 i0 = *(const float4*)(baseI + ys * 32);
            const float4 i1 = *(const float4*)(baseI + ys * 32 + 4);
            const bf16x8 bR = cvt8(r0, r1);
            const bf16x8 bI = cvt8(i0, i1);
            P = __builtin_amdgcn_mfma_f32_16x16x32_bf16(aR[ys], bR, P, 0, 0, 0);
            Q = __builtin_amdgcn_mfma_f32_16x16x32_bf16(aI[ys], bI, Q, 0, 0, 0);
            U = __builtin_amdgcn_mfma_f32_16x16x32_bf16(aR[ys], bI, U, 0, 0, 0);
            V = __builtin_amdgcn_mfma_f32_16x16x32_bf16(aI[ys], bR, V, 0, 0, 0);
        }

        // ---- Stage C: multiply by Ex[k,x], accumulate over this x-tile ----
        // C/D layout (m89-verified): col = lane&15 (x), row = (lane>>4)*4 + j
#pragma unroll
        for (int j = 0; j < 4; ++j) {
            const int kl = lg * 4 + j;
            const float TR = P[j] - Q[j];
            const float TI = U[j] + V[j];
            const float eR = exR[kl][x];
            const float eI = exI[kl][x];
            outRe[j] += eR * TR - eI * TI;
            outIm[j] += eR * TI + eI * TR;
        }
    }

    // ---- reduce over the 16 x-lanes; lanes with l15==0 write ----
#pragma unroll
    for (int j = 0; j < 4; ++j) {
        float r_ = outRe[j];
        float i_ = outIm[j];
#pragma unroll
        for (int m = 1; m < 16; m <<= 1) {
            r_ += __shfl_xor(r_, m, 64);
            i_ += __shfl_xor(i_, m, 64);
        }
        if (l15 == 0) {
            const int kg = k0 + lg * 4 + j;
            ((float2*)out)[c * K_TOTAL + kg] = make_float2(r_, i_);
        }
    }
}

extern "C" void kernel_launch(void* const* d_in, const int* in_sizes, int n_in,
                              void* d_out, int out_size, void* d_ws, size_t ws_size,
                              hipStream_t stream) {
    const float* imgR = (const float*)d_in[0];
    const float* imgI = (const float*)d_in[1];
    const float* trj  = (const float*)d_in[2];
    float* out = (float*)d_out;

    hipLaunchKernelGGL(nufft_mfma_kernel, dim3(K_TOTAL / KB), dim3(512), 0, stream,
                       imgR, imgI, trj, out);
}

// Round 7
// 28.433 us; speedup vs baseline: 2.2269x; 2.2269x over previous
//
#include <hip/hip_runtime.h>
#include <math.h>

// NUFFT forward via separable phase + bf16 MFMA. No workspace.
// ksp[c,k] = sum_x Ex[k,x] * ( sum_y img[c,x,y] * Ey[k,y] )
// R7: R4 skeleton (KB=32, grid 256, wave=coil, same output path — the only
// family that passed re-validation). Change: B-operand fed through LDS.
// Diagnosis: R4/R5 are L1 gather-transaction-bound (all pipes <19% busy;
// R5's 2 blocks/CU made it 1.64x SLOWER -> per-CU L1/TA is the shared
// limiter; fragment loads were 64-lane gathers spanning ~32 lines each).
// Fix: per x-tile, 512 threads cooperatively stage img slab (all 8 coils,
// 16 rows, fp32->bf16) into LDS with perfectly coalesced global loads;
// MFMA B-fragments come from LDS via XOR-swizzled ds_read_b128
// (byte ^= (row&15)<<4 -> conflict-free).

#define K_TOTAL 8192
#define KB      32          // k's per block
#define NX      128
#define NY      128
#define EY_LD   136         // bf16 row stride (pad +8)
#define EX_LD   132         // f32 row stride (pad +4)

typedef short  bf16x8 __attribute__((ext_vector_type(8)));
typedef float  f32x4  __attribute__((ext_vector_type(4)));

__device__ inline unsigned short f32_to_bf16_rne(float f) {
    unsigned int u = __float_as_uint(f);
    u += 0x7FFFu + ((u >> 16) & 1u);
    return (unsigned short)(u >> 16);
}

__global__ __launch_bounds__(512, 2) void nufft_mfma_kernel(
    const float* __restrict__ imgR,
    const float* __restrict__ imgI,
    const float* __restrict__ trj,
    float* __restrict__ out)
{
    __shared__ __align__(16) unsigned short eyR[KB][EY_LD];
    __shared__ __align__(16) unsigned short eyI[KB][EY_LD];
    __shared__ __align__(16) float exR[KB][EX_LD];
    __shared__ __align__(16) float exI[KB][EX_LD];
    // slab: [coil 8][x-row 16][y 128] bf16, 256 B/row, XOR-swizzled in-row
    __shared__ __align__(16) unsigned short slabR[8 * 16 * 128];
    __shared__ __align__(16) unsigned short slabI[8 * 16 * 128];

    const int tid = threadIdx.x;
    const int k0  = blockIdx.x * KB;

    // ---- Phase A: exponential tables (Ey bf16, Ex f32) ----
    for (int i = tid; i < KB * 128; i += 512) {
        const int kk = i >> 7;
        const int p  = i & 127;
        const float kx = trj[(k0 + kk) * 2 + 0];
        const float ky = trj[(k0 + kk) * 2 + 1];
        const float r  = (float)(p - 64) * (1.0f / 128.0f);

        float ty = -ky * r; ty -= floorf(ty);
        float sy, cy; __sincosf(6.283185307179586f * ty, &sy, &cy);
        eyR[kk][p] = f32_to_bf16_rne(cy);
        eyI[kk][p] = f32_to_bf16_rne(sy);

        float tx = -kx * r; tx -= floorf(tx);
        float sx, cx; __sincosf(6.283185307179586f * tx, &sx, &cx);
        exR[kk][p] = cx;
        exI[kk][p] = sx;
    }
    __syncthreads();

    const int wave = tid >> 6;      // 0..7  == coil
    const int lane = tid & 63;
    const int l15  = lane & 15;
    const int lg   = lane >> 4;     // 0..3

    // ---- A-fragment preload: Ey (R4-proven layout) ----
    // A layout (16x16x32): row = lane&15 (+16*kt), k slot = (lane>>4)*8 + idx.
    bf16x8 aR[2][4], aI[2][4];
#pragma unroll
    for (int kt = 0; kt < 2; ++kt)
#pragma unroll
        for (int ys = 0; ys < 4; ++ys) {
            const int row = kt * 16 + l15;
            const int y   = ys * 32 + lg * 8;
            aR[kt][ys] = *(const bf16x8*)&eyR[row][y];
            aI[kt][ys] = *(const bf16x8*)&eyI[row][y];
        }

    const int c = wave;
    f32x4 outRe[2] = {{0,0,0,0},{0,0,0,0}};
    f32x4 outIm[2] = {{0,0,0,0},{0,0,0,0}};

    // ---- n-tiles: 8 x-tiles of 16; slab staged cooperatively per tile ----
    for (int nt = 0; nt < 8; ++nt) {
        const int x0 = nt * 16;

        // ---- stage: coalesced fp32 loads -> bf16 -> swizzled LDS ----
        // q enumerates float4s of the slab: [c][xl][y4], y4 fastest ->
        // consecutive lanes read consecutive 16B (perfect coalescing).
#pragma unroll
        for (int i = 0; i < 8; ++i) {
            const int q   = tid + 512 * i;      // 0..4095
            const int qc  = q >> 9;             // coil
            const int rem = q & 511;
            const int xl  = rem >> 5;           // x within tile
            const int y4  = rem & 31;           // float4 within row
            const int gidx = (qc * NX + x0 + xl) * NY + y4 * 4;
            const float4 vR = *(const float4*)(imgR + gidx);
            const float4 vI = *(const float4*)(imgI + gidx);
            uint2 pR, pI;
            pR.x = (unsigned)f32_to_bf16_rne(vR.x) | ((unsigned)f32_to_bf16_rne(vR.y) << 16);
            pR.y = (unsigned)f32_to_bf16_rne(vR.z) | ((unsigned)f32_to_bf16_rne(vR.w) << 16);
            pI.x = (unsigned)f32_to_bf16_rne(vI.x) | ((unsigned)f32_to_bf16_rne(vI.y) << 16);
            pI.y = (unsigned)f32_to_bf16_rne(vI.z) | ((unsigned)f32_to_bf16_rne(vI.w) << 16);
            const int rowb = (qc * 16 + xl) * 256;                 // bytes
            const int inb  = (y4 * 8) ^ ((xl & 15) << 4);          // swizzle
            *(uint2*)((char*)slabR + rowb + inb) = pR;
            *(uint2*)((char*)slabI + rowb + inb) = pI;
        }
        __syncthreads();

        // ---- MFMA from LDS slab ----
        const int x = x0 + l15;
        f32x4 P[2] = {{0,0,0,0},{0,0,0,0}};
        f32x4 Q[2] = {{0,0,0,0},{0,0,0,0}};
        f32x4 U[2] = {{0,0,0,0},{0,0,0,0}};
        f32x4 V[2] = {{0,0,0,0},{0,0,0,0}};

        // B layout: col = lane&15 -> x-row l15; k slot y = (lane>>4)*8 + idx.
        const int rowb = (c * 16 + l15) * 256;
#pragma unroll
        for (int ys = 0; ys < 4; ++ys) {
            const int inb = (lg * 16 + ys * 64) ^ ((l15 & 15) << 4);
            const bf16x8 bR = *(const bf16x8*)((const char*)slabR + rowb + inb);
            const bf16x8 bI = *(const bf16x8*)((const char*)slabI + rowb + inb);
#pragma unroll
            for (int kt = 0; kt < 2; ++kt) {
                P[kt] = __builtin_amdgcn_mfma_f32_16x16x32_bf16(aR[kt][ys], bR, P[kt], 0, 0, 0);
                Q[kt] = __builtin_amdgcn_mfma_f32_16x16x32_bf16(aI[kt][ys], bI, Q[kt], 0, 0, 0);
                U[kt] = __builtin_amdgcn_mfma_f32_16x16x32_bf16(aR[kt][ys], bI, U[kt], 0, 0, 0);
                V[kt] = __builtin_amdgcn_mfma_f32_16x16x32_bf16(aI[kt][ys], bR, V[kt], 0, 0, 0);
            }
        }

        // ---- Stage C: multiply by Ex[k,x], accumulate over this x-tile ----
        // C/D layout (m89-verified): col = lane&15 (x), row = (lane>>4)*4 + j (+16*kt)
#pragma unroll
        for (int kt = 0; kt < 2; ++kt) {
#pragma unroll
            for (int j = 0; j < 4; ++j) {
                const int kl = kt * 16 + lg * 4 + j;
                const float TR = P[kt][j] - Q[kt][j];
                const float TI = U[kt][j] + V[kt][j];
                const float eR = exR[kl][x];
                const float eI = exI[kl][x];
                outRe[kt][j] += eR * TR - eI * TI;
                outIm[kt][j] += eR * TI + eI * TR;
            }
        }
        __syncthreads();   // slab reads done before next tile's staging
    }

    // ---- reduce over the 16 x-lanes; lanes with l15==0 write ----
#pragma unroll
    for (int kt = 0; kt < 2; ++kt) {
#pragma unroll
        for (int j = 0; j < 4; ++j) {
            float r_ = outRe[kt][j];
            float i_ = outIm[kt][j];
#pragma unroll
            for (int m = 1; m < 16; m <<= 1) {
                r_ += __shfl_xor(r_, m, 64);
                i_ += __shfl_xor(i_, m, 64);
            }
            if (l15 == 0) {
                const int kg = k0 + kt * 16 + lg * 4 + j;
                ((float2*)out)[c * K_TOTAL + kg] = make_float2(r_, i_);
            }
        }
    }
}

extern "C" void kernel_launch(void* const* d_in, const int* in_sizes, int n_in,
                              void* d_out, int out_size, void* d_ws, size_t ws_size,
                              hipStream_t stream) {
    const float* imgR = (const float*)d_in[0];
    const float* imgI = (const float*)d_in[1];
    const float* trj  = (const float*)d_in[2];
    float* out = (float*)d_out;

    hipLaunchKernelGGL(nufft_mfma_kernel, dim3(K_TOTAL / KB), dim3(512), 0, stream,
                       imgR, imgI, trj, out);
}